// Round 9
// baseline (172.630 us; speedup 1.0000x reference)
//
#include <hip/hip_runtime.h>
#include <hip/hip_bf16.h>

#define HW 36864  // 192*192
#define LOG2E 1.44269504088896f

typedef __attribute__((ext_vector_type(8))) short short8;   // 8 x bf16 (4 VGPR)
typedef __attribute__((ext_vector_type(16))) float f32x16;  // 32x32 MFMA C/D

__device__ __forceinline__ float BLO(unsigned u) { return __uint_as_float(u << 16); }
__device__ __forceinline__ float BHI(unsigned u) { return __uint_as_float(u & 0xffff0000u); }
__device__ __forceinline__ unsigned short f2bf(float f) {
    unsigned u = __float_as_uint(f);
    u += 0x7fffu + ((u >> 16) & 1u);   // RNE
    return (unsigned short)(u >> 16);
}
__device__ __forceinline__ unsigned pk2(float lo, float hi) {
    unsigned r;
    asm("v_cvt_pk_bf16_f32 %0, %1, %2" : "=v"(r) : "v"(lo), "v"(hi));
    return r;
}
__device__ __forceinline__ void plswap(unsigned &a, unsigned &b) {
    asm volatile("v_permlane32_swap_b32 %0, %1" : "+v"(a), "+v"(b));
}

union FragW { unsigned u[4]; short8 s; };

// d_ws: Xh [B*HW][64ch] bf16 NHWC records, 128 B/pixel (37.75 MB total).
// Lifecycle: to_nhwc writes x; attn1n overwrites with out1 (in-place, per-wave
// own records); attn2n overwrites with FINAL = g2*att2 + out1; to_nchw -> d_out.

// ---------------- K1: x NCHW f32 -> NHWC bf16 records ------------------------
__global__ __launch_bounds__(256) void to_nhwc_kernel(
    const float* __restrict__ x, char* __restrict__ xh)
{
    __shared__ unsigned lds[32 * 193];
    const int bid = blockIdx.x;
    const int b = bid / 192, y = bid % 192;
    const int tid = threadIdx.x;
    const int cp = tid >> 3, xq8 = tid & 7;

    const float4* rA = (const float4*)(x + ((size_t)b * 64 + 2 * cp) * HW + (size_t)y * 192);
    const float4* rB = (const float4*)(x + ((size_t)b * 64 + 2 * cp + 1) * HW + (size_t)y * 192);
    #pragma unroll
    for (int i = 0; i < 6; ++i) {
        const int f = 8 * i + xq8;
        const float4 a = rA[f];
        const float4 c = rB[f];
        const int px = f * 4;
        lds[cp * 193 + px + 0] = pk2(a.x, c.x);
        lds[cp * 193 + px + 1] = pk2(a.y, c.y);
        lds[cp * 193 + px + 2] = pk2(a.z, c.z);
        lds[cp * 193 + px + 3] = pk2(a.w, c.w);
    }
    __syncthreads();

    char* dst = xh + ((size_t)b * HW + (size_t)y * 192) * 128;
    #pragma unroll
    for (int j = 0; j < 6; ++j) {
        const int idx = j * 256 + tid;
        const int px = idx >> 3, q = idx & 7;
        uint4 v;
        v.x = lds[(4 * q + 0) * 193 + px];
        v.y = lds[(4 * q + 1) * 193 + px];
        v.z = lds[(4 * q + 2) * 193 + px];
        v.w = lds[(4 * q + 3) * 193 + px];
        *(uint4*)(dst + px * 128 + q * 16) = v;
    }
}

// ---------------- K2: 4x4 window attention, NHWC in-place --------------------
// Block = 16 windows (4 waves x 4 windows); wave reads only its own 64 records.
__global__ __launch_bounds__(256) void attn1n_kernel(
    char* __restrict__ xh,
    const float* __restrict__ wq, const float* __restrict__ bq,
    const float* __restrict__ wk, const float* __restrict__ bk,
    const float* __restrict__ wv, const float* __restrict__ bv,
    const float* __restrict__ gamma)
{
    __shared__ char smem[4 * 8192];

    const int tid   = threadIdx.x;
    const int wv_id = tid >> 6;
    const int lane  = tid & 63;
    const int l32   = lane & 31;
    const int h     = lane >> 5;
    char* VsW = smem + wv_id * 8192;

    const int gw0 = blockIdx.x * 16 + wv_id * 4;

    f32x16 zf;
    #pragma unroll
    for (int r = 0; r < 16; ++r) zf[r] = 0.f;

    // weight/bias fragments (float4 loads)
    FragW wqkf[4], wvf[2][4];
    {
        const float4* wrow4 = (const float4*)((l32 < 16) ? (wq + l32 * 64)
                                                         : (wk + (l32 - 16) * 64));
        #pragma unroll
        for (int cc = 0; cc < 4; ++cc) {
            const float4 a = wrow4[cc * 4 + 2 * h];
            const float4 b = wrow4[cc * 4 + 2 * h + 1];
            wqkf[cc].u[0] = pk2(a.x, a.y); wqkf[cc].u[1] = pk2(a.z, a.w);
            wqkf[cc].u[2] = pk2(b.x, b.y); wqkf[cc].u[3] = pk2(b.z, b.w);
        }
        #pragma unroll
        for (int ot = 0; ot < 2; ++ot) {
            const float4* wvr4 = (const float4*)(wv + (size_t)(ot * 32 + l32) * 64);
            #pragma unroll
            for (int cc = 0; cc < 4; ++cc) {
                const float4 a = wvr4[cc * 4 + 2 * h];
                const float4 b = wvr4[cc * 4 + 2 * h + 1];
                wvf[ot][cc].u[0] = pk2(a.x, a.y); wvf[ot][cc].u[1] = pk2(a.z, a.w);
                wvf[ot][cc].u[2] = pk2(b.x, b.y); wvf[ot][cc].u[3] = pk2(b.z, b.w);
            }
        }
    }
    float bqv[8], bkv[8], bvv[2][16];
    #pragma unroll
    for (int r = 0; r < 8; ++r) {
        const int c = (r & 3) + 8 * (r >> 2) + 4 * h;
        bqv[r] = bq[c];
        bkv[r] = bk[c];
    }
    #pragma unroll
    for (int ot = 0; ot < 2; ++ot)
        #pragma unroll
        for (int r = 0; r < 16; ++r)
            bvv[ot][r] = bv[ot * 32 + (r & 3) + 8 * (r >> 2) + 4 * h];

    // identity A-frags: I_lo lifts chunk ch 0..15 -> rows 0..15, I_hi -> rows 16..31
    FragW Ilo, Ihi;
    #pragma unroll
    for (int j = 0; j < 4; ++j) {
        const int k0 = 8 * h + 2 * j;
        unsigned lo  = (l32 == k0)      ? 0x3F80u : 0u;
        unsigned hi  = (l32 == k0 + 1)  ? 0x3F80u : 0u;
        Ilo.u[j] = lo | (hi << 16);
        unsigned lo2 = (l32 == 16 + k0)     ? 0x3F80u : 0u;
        unsigned hi2 = (l32 == 16 + k0 + 1) ? 0x3F80u : 0u;
        Ihi.u[j] = lo2 | (hi2 << 16);
    }

    size_t px1[2];
    #pragma unroll
    for (int t = 0; t < 2; ++t) {
        const int gwin = gw0 + 2 * t + (l32 >> 4);
        const int b = gwin / 2304;
        const int rem = gwin % 2304;
        const int Y = rem / 48, X = rem % 48;
        const int yy = Y * 4 + ((l32 >> 2) & 3);
        const int xx = X * 4 + (l32 & 3);
        px1[t] = ((size_t)b * HW + (size_t)yy * 192 + xx) * 128;
    }

    FragW qf[2], kf[2];
    #pragma unroll
    for (int t = 0; t < 2; ++t) {
        const char* rec = xh + px1[t];
        FragW xw[4];
        #pragma unroll
        for (int cc = 0; cc < 4; ++cc)
            xw[cc].s = *(const short8*)(rec + cc * 32 + 16 * h);

        f32x16 dqk = zf;
        #pragma unroll
        for (int cc = 0; cc < 4; ++cc)
            dqk = __builtin_amdgcn_mfma_f32_32x32x16_bf16(wqkf[cc].s, xw[cc].s, dqk, 0, 0, 0);

        {
            float q0[8];
            #pragma unroll
            for (int r = 0; r < 8; ++r) q0[r] = (dqk[r] + bqv[r]) * LOG2E;
            unsigned A0 = pk2(q0[0], q0[1]), B0 = pk2(q0[2], q0[3]);
            unsigned C0 = pk2(q0[4], q0[5]), D0 = pk2(q0[6], q0[7]);
            plswap(A0, C0); plswap(B0, D0);
            qf[t].u[0] = A0; qf[t].u[1] = B0; qf[t].u[2] = C0; qf[t].u[3] = D0;
        }
        {
            float k0[8];
            #pragma unroll
            for (int r = 0; r < 8; ++r) k0[r] = dqk[8 + r] + bkv[r];
            unsigned A0 = pk2(k0[0], k0[1]), B0 = pk2(k0[2], k0[3]);
            unsigned C0 = pk2(k0[4], k0[5]), D0 = pk2(k0[6], k0[7]);
            plswap(A0, C0); plswap(B0, D0);
            kf[t].u[0] = A0; kf[t].u[1] = B0; kf[t].u[2] = C0; kf[t].u[3] = D0;
        }

        #pragma unroll
        for (int ot = 0; ot < 2; ++ot) {
            f32x16 dv = zf;
            #pragma unroll
            for (int cc = 0; cc < 4; ++cc)
                dv = __builtin_amdgcn_mfma_f32_32x32x16_bf16(wvf[ot][cc].s, xw[cc].s, dv, 0, 0, 0);
            #pragma unroll
            for (int r = 0; r < 16; ++r) {
                const int ch = ot * 32 + (r & 3) + 8 * (r >> 2) + 4 * h;
                *(unsigned short*)(VsW + ((ch * 128 + 2 * (t * 32 + l32)) ^ ((ch & 7) << 4)))
                    = f2bf(dv[r] + bvv[ot][r]);
            }
        }
    }
    __syncthreads();

    const float g = gamma[0];
    const bool wa = (l32 < 16);

    #pragma unroll
    for (int t = 0; t < 2; ++t) {
        f32x16 sT = __builtin_amdgcn_mfma_f32_32x32x16_bf16(kf[t].s, qf[t].s, zf, 0, 0, 0);

        float e[8];
        #pragma unroll
        for (int j = 0; j < 8; ++j) e[j] = exp2f(wa ? sT[j] : sT[8 + j]);
        float ls = ((e[0] + e[1]) + (e[2] + e[3])) + ((e[4] + e[5]) + (e[6] + e[7]));
        ls += __shfl_xor(ls, 32);

        unsigned A0 = pk2(e[0], e[1]), B0 = pk2(e[2], e[3]);
        unsigned C0 = pk2(e[4], e[5]), D0 = pk2(e[6], e[7]);
        plswap(A0, C0); plswap(B0, D0);
        FragW pa, pb;
        pa.u[0] = wa ? A0 : 0u; pa.u[1] = wa ? B0 : 0u;
        pa.u[2] = wa ? C0 : 0u; pa.u[3] = wa ? D0 : 0u;
        pb.u[0] = wa ? 0u : A0; pb.u[1] = wa ? 0u : B0;
        pb.u[2] = wa ? 0u : C0; pb.u[3] = wa ? 0u : D0;

        f32x16 acc0 = zf, acc1 = zf;
        #pragma unroll
        for (int wsx = 0; wsx < 2; ++wsx) {
            const short8 pfrag = wsx ? pb.s : pa.s;
            const int mbase = t * 64 + wsx * 32 + 16 * h;
            const int ch0 = l32, ch1 = 32 + l32;
            const short8 v0 = *(const short8*)(VsW + ((ch0 * 128 + mbase) ^ ((ch0 & 7) << 4)));
            const short8 v1 = *(const short8*)(VsW + ((ch1 * 128 + mbase) ^ ((ch1 & 7) << 4)));
            acc0 = __builtin_amdgcn_mfma_f32_32x32x16_bf16(v0, pfrag, acc0, 0, 0, 0);
            acc1 = __builtin_amdgcn_mfma_f32_32x32x16_bf16(v1, pfrag, acc1, 0, 0, 0);
        }

        const float inv = 1.f / ls;

        // residual from own record via identity MFMA (exact D-layout)
        char* rec = xh + px1[t];
        FragW x0, x1, x2, x3;
        x0.s = *(const short8*)(rec + 0 * 32 + 16 * h);
        x1.s = *(const short8*)(rec + 1 * 32 + 16 * h);
        x2.s = *(const short8*)(rec + 2 * 32 + 16 * h);
        x3.s = *(const short8*)(rec + 3 * 32 + 16 * h);
        f32x16 r01 = __builtin_amdgcn_mfma_f32_32x32x16_bf16(Ihi.s, x1.s, zf, 0, 0, 0);
        r01 = __builtin_amdgcn_mfma_f32_32x32x16_bf16(Ilo.s, x0.s, r01, 0, 0, 0);
        f32x16 r23 = __builtin_amdgcn_mfma_f32_32x32x16_bf16(Ihi.s, x3.s, zf, 0, 0, 0);
        r23 = __builtin_amdgcn_mfma_f32_32x32x16_bf16(Ilo.s, x2.s, r23, 0, 0, 0);

        #pragma unroll
        for (int q = 0; q < 4; ++q) {
            const float a0 = fmaf(g, acc0[4*q+0] * inv, r01[4*q+0]);
            const float a1 = fmaf(g, acc0[4*q+1] * inv, r01[4*q+1]);
            const float a2 = fmaf(g, acc0[4*q+2] * inv, r01[4*q+2]);
            const float a3 = fmaf(g, acc0[4*q+3] * inv, r01[4*q+3]);
            uint2 wA; wA.x = pk2(a0, a1); wA.y = pk2(a2, a3);
            *(uint2*)(rec + 16 * q + 8 * h) = wA;
            const float b0 = fmaf(g, acc1[4*q+0] * inv, r23[4*q+0]);
            const float b1 = fmaf(g, acc1[4*q+1] * inv, r23[4*q+1]);
            const float b2 = fmaf(g, acc1[4*q+2] * inv, r23[4*q+2]);
            const float b3 = fmaf(g, acc1[4*q+3] * inv, r23[4*q+3]);
            uint2 wB; wB.x = pk2(b0, b1); wB.y = pk2(b2, b3);
            *(uint2*)(rec + 64 + 16 * q + 8 * h) = wB;
        }
    }
}

// ---------------- K3: 8x8 chess proj + attention + final fold, in-place ------
#define KT_OFF 0
#define VS_OFF 18432

__global__ __launch_bounds__(576) void attn2n_kernel(
    char* __restrict__ xh,
    const float* __restrict__ wq, const float* __restrict__ bq,
    const float* __restrict__ wk, const float* __restrict__ bk,
    const float* __restrict__ wv, const float* __restrict__ bv,
    const float* __restrict__ gamma)
{
    __shared__ char smem[92160];   // Kt 18432 + Vs 73728

    const int wid = blockIdx.x;
    const int b  = wid >> 6;
    const int a  = wid & 7;
    const int c0 = (wid >> 3) & 7;

    const int tid = threadIdx.x;
    const int wv_id = tid >> 6;
    const int l32 = tid & 31;
    const int h   = (tid >> 5) & 1;
    const int n0  = wv_id * 64;

    f32x16 zf;
    #pragma unroll
    for (int r = 0; r < 16; ++r) zf[r] = 0.f;

    FragW wqkf[4], wvf[2][4];
    {
        const float4* wrow4 = (const float4*)((l32 < 16) ? (wq + l32 * 64)
                                                         : (wk + (l32 - 16) * 64));
        #pragma unroll
        for (int cc = 0; cc < 4; ++cc) {
            const float4 a4 = wrow4[cc * 4 + 2 * h];
            const float4 b4 = wrow4[cc * 4 + 2 * h + 1];
            wqkf[cc].u[0] = pk2(a4.x, a4.y); wqkf[cc].u[1] = pk2(a4.z, a4.w);
            wqkf[cc].u[2] = pk2(b4.x, b4.y); wqkf[cc].u[3] = pk2(b4.z, b4.w);
        }
        #pragma unroll
        for (int ot = 0; ot < 2; ++ot) {
            const float4* wvr4 = (const float4*)(wv + (size_t)(ot * 32 + l32) * 64);
            #pragma unroll
            for (int cc = 0; cc < 4; ++cc) {
                const float4 a4 = wvr4[cc * 4 + 2 * h];
                const float4 b4 = wvr4[cc * 4 + 2 * h + 1];
                wvf[ot][cc].u[0] = pk2(a4.x, a4.y); wvf[ot][cc].u[1] = pk2(a4.z, a4.w);
                wvf[ot][cc].u[2] = pk2(b4.x, b4.y); wvf[ot][cc].u[3] = pk2(b4.z, b4.w);
            }
        }
    }
    float bias_qk[16], bvv[2][16];
    #pragma unroll
    for (int r = 0; r < 8; ++r) {
        const int c = (r & 3) + 8 * (r >> 2) + 4 * h;
        bias_qk[r] = bq[c];
        bias_qk[8 + r] = bk[c];
    }
    #pragma unroll
    for (int ot = 0; ot < 2; ++ot)
        #pragma unroll
        for (int r = 0; r < 16; ++r)
            bvv[ot][r] = bv[ot * 32 + (r & 3) + 8 * (r >> 2) + 4 * h];

    // identity A-frags (residual lift)
    FragW Ilo, Ihi;
    #pragma unroll
    for (int j = 0; j < 4; ++j) {
        const int k0 = 8 * h + 2 * j;
        unsigned lo  = (l32 == k0)      ? 0x3F80u : 0u;
        unsigned hi  = (l32 == k0 + 1)  ? 0x3F80u : 0u;
        Ilo.u[j] = lo | (hi << 16);
        unsigned lo2 = (l32 == 16 + k0)     ? 0x3F80u : 0u;
        unsigned hi2 = (l32 == 16 + k0 + 1) ? 0x3F80u : 0u;
        Ihi.u[j] = lo2 | (hi2 << 16);
    }
    // all-ones A-frag (softmax denominator via MFMA column-sum)
    FragW ones;
    ones.u[0] = ones.u[1] = ones.u[2] = ones.u[3] = 0x3F803F80u;

    size_t prec[2];
    FragW qfr[2];
    #pragma unroll
    for (int t = 0; t < 2; ++t) {
        const int m = n0 + t * 32 + l32;
        const int i = m / 24, j = m - i * 24;
        prec[t] = ((size_t)b * HW + (size_t)(a + 8 * i) * 192 + (c0 + 8 * j)) * 128;
        const char* rec = xh + prec[t];

        FragW xw[4];
        #pragma unroll
        for (int cc = 0; cc < 4; ++cc)
            xw[cc].s = *(const short8*)(rec + cc * 32 + 16 * h);

        f32x16 dqk = zf;
        #pragma unroll
        for (int cc = 0; cc < 4; ++cc)
            dqk = __builtin_amdgcn_mfma_f32_32x32x16_bf16(wqkf[cc].s, xw[cc].s, dqk, 0, 0, 0);

        {   // Q B-frag, pre-scaled by log2(e) so the loop uses exp2 directly
            float q0[8];
            #pragma unroll
            for (int r = 0; r < 8; ++r) q0[r] = (dqk[r] + bias_qk[r]) * LOG2E;
            unsigned A0 = pk2(q0[0], q0[1]), B0 = pk2(q0[2], q0[3]);
            unsigned C0 = pk2(q0[4], q0[5]), D0 = pk2(q0[6], q0[7]);
            plswap(A0, C0); plswap(B0, D0);
            qfr[t].u[0] = A0; qfr[t].u[1] = B0; qfr[t].u[2] = C0; qfr[t].u[3] = D0;
        }
        #pragma unroll
        for (int r = 8; r < 16; ++r) {
            const int c = (r & 3) + 8 * ((r >> 2) & 1) + 4 * h;
            *(unsigned short*)(smem + KT_OFF + ((m * 32 + 2 * c) ^ (((m >> 2) & 3) << 4)))
                = f2bf(dqk[r] + bias_qk[r]);
        }
        #pragma unroll
        for (int ot = 0; ot < 2; ++ot) {
            f32x16 dv = zf;
            #pragma unroll
            for (int cc = 0; cc < 4; ++cc)
                dv = __builtin_amdgcn_mfma_f32_32x32x16_bf16(wvf[ot][cc].s, xw[cc].s, dv, 0, 0, 0);
            #pragma unroll
            for (int r = 0; r < 16; ++r) {
                const int ch = ot * 32 + (r & 3) + 8 * (r >> 2) + 4 * h;
                *(unsigned short*)(smem + VS_OFF + ((ch * 1152 + 2 * m) ^ ((ch & 7) << 4)))
                    = f2bf(dv[r] + bvv[ot][r]);
            }
        }
    }
    __syncthreads();

    const short8 qf0 = qfr[0].s, qf1 = qfr[1].s;
    f32x16 accA = zf, accB = zf, accC = zf, accD = zf;
    f32x16 accS0 = zf, accS1 = zf;   // softmax denominators via ones-MFMA
    const int chA = l32, chB = 32 + l32;
    const int swzA = (chA & 7) << 4, swzB = (chB & 7) << 4;

    // K-fragment register prefetch (tile 0)
    short8 kfc = *(const short8*)(smem + KT_OFF + ((l32 * 32 + 16 * h) ^ (((l32 >> 2) & 3) << 4)));

    #pragma unroll 1
    for (int mt = 0; mt < 18; ++mt) {
        const int m0 = mt * 32;

        // prefetch next K-fragment before the compute chain
        short8 kfn = kfc;
        if (mt < 17) {
            const int mr = m0 + 32 + l32;
            kfn = *(const short8*)(smem + KT_OFF + ((mr * 32 + 16 * h) ^ (((mr >> 2) & 3) << 4)));
        }

        f32x16 s0 = __builtin_amdgcn_mfma_f32_32x32x16_bf16(kfc, qf0, zf, 0, 0, 0);
        f32x16 s1 = __builtin_amdgcn_mfma_f32_32x32x16_bf16(kfc, qf1, zf, 0, 0, 0);

        const short8 vA0 = *(const short8*)(smem + VS_OFF + ((chA * 1152 + 2 * (m0 + 8 * h)) ^ swzA));
        const short8 vA1 = *(const short8*)(smem + VS_OFF + ((chA * 1152 + 2 * (m0 + 16 + 8 * h)) ^ swzA));
        const short8 vB0 = *(const short8*)(smem + VS_OFF + ((chB * 1152 + 2 * (m0 + 8 * h)) ^ swzB));
        const short8 vB1 = *(const short8*)(smem + VS_OFF + ((chB * 1152 + 2 * (m0 + 16 + 8 * h)) ^ swzB));

        #pragma unroll
        for (int r = 0; r < 16; ++r) s0[r] = exp2f(s0[r]);
        #pragma unroll
        for (int r = 0; r < 16; ++r) s1[r] = exp2f(s1[r]);

        FragW pf00, pf01, pf10, pf11;
        {
            unsigned A0 = pk2(s0[0], s0[1]), B0 = pk2(s0[2], s0[3]);
            unsigned C0 = pk2(s0[4], s0[5]), D0 = pk2(s0[6], s0[7]);
            plswap(A0, C0); plswap(B0, D0);
            pf00.u[0] = A0; pf00.u[1] = B0; pf00.u[2] = C0; pf00.u[3] = D0;
            unsigned E0 = pk2(s0[8], s0[9]),  F0 = pk2(s0[10], s0[11]);
            unsigned G0 = pk2(s0[12], s0[13]), H0 = pk2(s0[14], s0[15]);
            plswap(E0, G0); plswap(F0, H0);
            pf01.u[0] = E0; pf01.u[1] = F0; pf01.u[2] = G0; pf01.u[3] = H0;
            unsigned A1 = pk2(s1[0], s1[1]), B1 = pk2(s1[2], s1[3]);
            unsigned C1 = pk2(s1[4], s1[5]), D1 = pk2(s1[6], s1[7]);
            plswap(A1, C1); plswap(B1, D1);
            pf10.u[0] = A1; pf10.u[1] = B1; pf10.u[2] = C1; pf10.u[3] = D1;
            unsigned E1 = pk2(s1[8], s1[9]),  F1 = pk2(s1[10], s1[11]);
            unsigned G1 = pk2(s1[12], s1[13]), H1 = pk2(s1[14], s1[15]);
            plswap(E1, G1); plswap(F1, H1);
            pf11.u[0] = E1; pf11.u[1] = F1; pf11.u[2] = G1; pf11.u[3] = H1;
        }

        accA = __builtin_amdgcn_mfma_f32_32x32x16_bf16(vA0, pf00.s, accA, 0, 0, 0);
        accA = __builtin_amdgcn_mfma_f32_32x32x16_bf16(vA1, pf01.s, accA, 0, 0, 0);
        accB = __builtin_amdgcn_mfma_f32_32x32x16_bf16(vB0, pf00.s, accB, 0, 0, 0);
        accB = __builtin_amdgcn_mfma_f32_32x32x16_bf16(vB1, pf01.s, accB, 0, 0, 0);
        accC = __builtin_amdgcn_mfma_f32_32x32x16_bf16(vA0, pf10.s, accC, 0, 0, 0);
        accC = __builtin_amdgcn_mfma_f32_32x32x16_bf16(vA1, pf11.s, accC, 0, 0, 0);
        accD = __builtin_amdgcn_mfma_f32_32x32x16_bf16(vB0, pf10.s, accD, 0, 0, 0);
        accD = __builtin_amdgcn_mfma_f32_32x32x16_bf16(vB1, pf11.s, accD, 0, 0, 0);

        // denominator: column sums of bf16(P) via all-ones A-frag
        accS0 = __builtin_amdgcn_mfma_f32_32x32x16_bf16(ones.s, pf00.s, accS0, 0, 0, 0);
        accS0 = __builtin_amdgcn_mfma_f32_32x32x16_bf16(ones.s, pf01.s, accS0, 0, 0, 0);
        accS1 = __builtin_amdgcn_mfma_f32_32x32x16_bf16(ones.s, pf10.s, accS1, 0, 0, 0);
        accS1 = __builtin_amdgcn_mfma_f32_32x32x16_bf16(ones.s, pf11.s, accS1, 0, 0, 0);

        kfc = kfn;
    }

    const float g2 = gamma[0];
    const float inv0 = 1.f / accS0[0], inv1 = 1.f / accS1[0];

    // final = g2 * att + out1 (residual via identity MFMA), in-place per tile
    #pragma unroll
    for (int t = 0; t < 2; ++t) {
        char* rec = xh + prec[t];
        FragW x0, x1, x2, x3;
        x0.s = *(const short8*)(rec + 0 * 32 + 16 * h);
        x1.s = *(const short8*)(rec + 1 * 32 + 16 * h);
        x2.s = *(const short8*)(rec + 2 * 32 + 16 * h);
        x3.s = *(const short8*)(rec + 3 * 32 + 16 * h);
        f32x16 r01 = __builtin_amdgcn_mfma_f32_32x32x16_bf16(Ihi.s, x1.s, zf, 0, 0, 0);
        r01 = __builtin_amdgcn_mfma_f32_32x32x16_bf16(Ilo.s, x0.s, r01, 0, 0, 0);
        f32x16 r23 = __builtin_amdgcn_mfma_f32_32x32x16_bf16(Ihi.s, x3.s, zf, 0, 0, 0);
        r23 = __builtin_amdgcn_mfma_f32_32x32x16_bf16(Ilo.s, x2.s, r23, 0, 0, 0);

        const f32x16 aclo = t ? accC : accA;
        const f32x16 achi = t ? accD : accB;
        const float inv = t ? inv1 : inv0;

        #pragma unroll
        for (int q = 0; q < 4; ++q) {
            const float a0 = fmaf(g2, aclo[4*q+0] * inv, r01[4*q+0]);
            const float a1 = fmaf(g2, aclo[4*q+1] * inv, r01[4*q+1]);
            const float a2 = fmaf(g2, aclo[4*q+2] * inv, r01[4*q+2]);
            const float a3 = fmaf(g2, aclo[4*q+3] * inv, r01[4*q+3]);
            uint2 wA; wA.x = pk2(a0, a1); wA.y = pk2(a2, a3);
            *(uint2*)(rec + 16 * q + 8 * h) = wA;
            const float b0 = fmaf(g2, achi[4*q+0] * inv, r23[4*q+0]);
            const float b1 = fmaf(g2, achi[4*q+1] * inv, r23[4*q+1]);
            const float b2 = fmaf(g2, achi[4*q+2] * inv, r23[4*q+2]);
            const float b3 = fmaf(g2, achi[4*q+3] * inv, r23[4*q+3]);
            uint2 wB; wB.x = pk2(b0, b1); wB.y = pk2(b2, b3);
            *(uint2*)(rec + 64 + 16 * q + 8 * h) = wB;
        }
    }
}

// ---------------- K4: NHWC bf16 records -> out NCHW f32 (write-only) ---------
__global__ __launch_bounds__(256) void to_nchw_kernel(
    float* __restrict__ out, const char* __restrict__ xh)
{
    __shared__ char smem[24576];

    const int bid = blockIdx.x;
    const int b = bid / 192, y = bid % 192;
    const int tid = threadIdx.x;

    const char* src = xh + ((size_t)b * HW + (size_t)y * 192) * 128;
    #pragma unroll
    for (int k = 0; k < 6; ++k) {
        const int off = k * 4096 + tid * 16;
        const int xq = off >> 7;
        const int gq = (off >> 4) & 7;
        const short8 v = *(const short8*)(src + off);
        *(short8*)(smem + (xq << 7) + (((gq ^ (xq & 7)) << 4))) = v;
    }
    __syncthreads();

    const int w = tid >> 6, lane = tid & 63;
    const size_t rowbase = (size_t)b * 64 * HW + (size_t)y * 192;

    #pragma unroll
    for (int it = 0; it < 24; ++it) {
        const int tt = it * 4 + w;
        const int chp = tt & 31;
        const int xb = tt >> 5;
        const int xx = xb * 64 + lane;
        const int byte_in_rec = chp * 4;
        const int gq = byte_in_rec >> 4;
        const unsigned v = *(const unsigned*)(smem + (xx << 7)
                            + ((gq ^ (xx & 7)) << 4) + (byte_in_rec & 15));
        const size_t o0 = rowbase + (size_t)(2 * chp) * HW + xx;
        out[o0]      = BLO(v);
        out[o0 + HW] = BHI(v);
    }
}

extern "C" void kernel_launch(void* const* d_in, const int* in_sizes, int n_in,
                              void* d_out, int out_size, void* d_ws, size_t ws_size,
                              hipStream_t stream)
{
    const float* x   = (const float*)d_in[0];
    const float* wq1 = (const float*)d_in[1];
    const float* bq1 = (const float*)d_in[2];
    const float* wk1 = (const float*)d_in[3];
    const float* bk1 = (const float*)d_in[4];
    const float* wv1 = (const float*)d_in[5];
    const float* bv1 = (const float*)d_in[6];
    const float* wq2 = (const float*)d_in[7];
    const float* bq2 = (const float*)d_in[8];
    const float* wk2 = (const float*)d_in[9];
    const float* bk2 = (const float*)d_in[10];
    const float* wv2 = (const float*)d_in[11];
    const float* bv2 = (const float*)d_in[12];
    const float* g1  = (const float*)d_in[13];
    const float* g2  = (const float*)d_in[14];
    float* out = (float*)d_out;
    char* xh = (char*)d_ws;

    to_nhwc_kernel<<<dim3(1536), dim3(256), 0, stream>>>(x, xh);

    attn1n_kernel<<<dim3(1152), dim3(256), 0, stream>>>(
        xh, wq1, bq1, wk1, bk1, wv1, bv1, g1);

    attn2n_kernel<<<dim3(512), dim3(576), 0, stream>>>(
        xh, wq2, bq2, wk2, bk2, wv2, bv2, g2);

    to_nchw_kernel<<<dim3(1536), dim3(256), 0, stream>>>(out, xh);
}

// Round 10
// 149.959 us; speedup vs baseline: 1.1512x; 1.1512x over previous
//
#include <hip/hip_runtime.h>
#include <hip/hip_bf16.h>

#define HW 36864  // 192*192
#define LOG2E 1.44269504088896f

typedef __attribute__((ext_vector_type(8))) short short8;   // 8 x bf16 (4 VGPR)
typedef __attribute__((ext_vector_type(16))) float f32x16;  // 32x32 MFMA C/D

__device__ __forceinline__ float BLO(unsigned u) { return __uint_as_float(u << 16); }
__device__ __forceinline__ float BHI(unsigned u) { return __uint_as_float(u & 0xffff0000u); }
__device__ __forceinline__ unsigned short f2bf(float f) {
    unsigned u = __float_as_uint(f);
    u += 0x7fffu + ((u >> 16) & 1u);   // RNE
    return (unsigned short)(u >> 16);
}
__device__ __forceinline__ unsigned pk2(float lo, float hi) {
    unsigned r;
    asm("v_cvt_pk_bf16_f32 %0, %1, %2" : "=v"(r) : "v"(lo), "v"(hi));
    return r;
}
__device__ __forceinline__ void plswap(unsigned &a, unsigned &b) {
    asm volatile("v_permlane32_swap_b32 %0, %1" : "+v"(a), "+v"(b));
}
// single-instruction 2^x (inputs here are bounded |x| < ~30, no denormal fixup needed)
__device__ __forceinline__ float fexp2(float x) {
    float r;
    asm("v_exp_f32 %0, %1" : "=v"(r) : "v"(x));
    return r;
}

union FragW { unsigned u[4]; short8 s; };

// d_ws: Xh [B*HW][64ch] bf16 NHWC records, 128 B/pixel (37.75 MB total).
// Lifecycle: to_nhwc writes x; attn1n overwrites with out1 (in-place, per-wave
// own records); attn2n overwrites with FINAL = g2*att2 + out1; to_nchw -> d_out.

// ---------------- K1: x NCHW f32 -> NHWC bf16 records ------------------------
__global__ __launch_bounds__(256) void to_nhwc_kernel(
    const float* __restrict__ x, char* __restrict__ xh)
{
    __shared__ unsigned lds[32 * 193];
    const int bid = blockIdx.x;
    const int b = bid / 192, y = bid % 192;
    const int tid = threadIdx.x;
    const int cp = tid >> 3, xq8 = tid & 7;

    const float4* rA = (const float4*)(x + ((size_t)b * 64 + 2 * cp) * HW + (size_t)y * 192);
    const float4* rB = (const float4*)(x + ((size_t)b * 64 + 2 * cp + 1) * HW + (size_t)y * 192);
    #pragma unroll
    for (int i = 0; i < 6; ++i) {
        const int f = 8 * i + xq8;
        const float4 a = rA[f];
        const float4 c = rB[f];
        const int px = f * 4;
        lds[cp * 193 + px + 0] = pk2(a.x, c.x);
        lds[cp * 193 + px + 1] = pk2(a.y, c.y);
        lds[cp * 193 + px + 2] = pk2(a.z, c.z);
        lds[cp * 193 + px + 3] = pk2(a.w, c.w);
    }
    __syncthreads();

    char* dst = xh + ((size_t)b * HW + (size_t)y * 192) * 128;
    #pragma unroll
    for (int j = 0; j < 6; ++j) {
        const int idx = j * 256 + tid;
        const int px = idx >> 3, q = idx & 7;
        uint4 v;
        v.x = lds[(4 * q + 0) * 193 + px];
        v.y = lds[(4 * q + 1) * 193 + px];
        v.z = lds[(4 * q + 2) * 193 + px];
        v.w = lds[(4 * q + 3) * 193 + px];
        *(uint4*)(dst + px * 128 + q * 16) = v;
    }
}

// ---------------- K2: 4x4 window attention, NHWC in-place --------------------
// Block = 16 windows (4 waves x 4 windows); wave reads only its own 64 records.
__global__ __launch_bounds__(256) void attn1n_kernel(
    char* __restrict__ xh,
    const float* __restrict__ wq, const float* __restrict__ bq,
    const float* __restrict__ wk, const float* __restrict__ bk,
    const float* __restrict__ wv, const float* __restrict__ bv,
    const float* __restrict__ gamma)
{
    __shared__ char smem[4 * 8192];

    const int tid   = threadIdx.x;
    const int wv_id = tid >> 6;
    const int lane  = tid & 63;
    const int l32   = lane & 31;
    const int h     = lane >> 5;
    char* VsW = smem + wv_id * 8192;

    const int gw0 = blockIdx.x * 16 + wv_id * 4;

    f32x16 zf;
    #pragma unroll
    for (int r = 0; r < 16; ++r) zf[r] = 0.f;

    // weight/bias fragments (float4 loads)
    FragW wqkf[4], wvf[2][4];
    {
        const float4* wrow4 = (const float4*)((l32 < 16) ? (wq + l32 * 64)
                                                         : (wk + (l32 - 16) * 64));
        #pragma unroll
        for (int cc = 0; cc < 4; ++cc) {
            const float4 a = wrow4[cc * 4 + 2 * h];
            const float4 b = wrow4[cc * 4 + 2 * h + 1];
            wqkf[cc].u[0] = pk2(a.x, a.y); wqkf[cc].u[1] = pk2(a.z, a.w);
            wqkf[cc].u[2] = pk2(b.x, b.y); wqkf[cc].u[3] = pk2(b.z, b.w);
        }
        #pragma unroll
        for (int ot = 0; ot < 2; ++ot) {
            const float4* wvr4 = (const float4*)(wv + (size_t)(ot * 32 + l32) * 64);
            #pragma unroll
            for (int cc = 0; cc < 4; ++cc) {
                const float4 a = wvr4[cc * 4 + 2 * h];
                const float4 b = wvr4[cc * 4 + 2 * h + 1];
                wvf[ot][cc].u[0] = pk2(a.x, a.y); wvf[ot][cc].u[1] = pk2(a.z, a.w);
                wvf[ot][cc].u[2] = pk2(b.x, b.y); wvf[ot][cc].u[3] = pk2(b.z, b.w);
            }
        }
    }
    float bqv[8], bkv[8], bvv[2][16];
    #pragma unroll
    for (int r = 0; r < 8; ++r) {
        const int c = (r & 3) + 8 * (r >> 2) + 4 * h;
        bqv[r] = bq[c];
        bkv[r] = bk[c];
    }
    #pragma unroll
    for (int ot = 0; ot < 2; ++ot)
        #pragma unroll
        for (int r = 0; r < 16; ++r)
            bvv[ot][r] = bv[ot * 32 + (r & 3) + 8 * (r >> 2) + 4 * h];

    // identity A-frags: I_lo lifts chunk ch 0..15 -> rows 0..15, I_hi -> rows 16..31
    FragW Ilo, Ihi;
    #pragma unroll
    for (int j = 0; j < 4; ++j) {
        const int k0 = 8 * h + 2 * j;
        unsigned lo  = (l32 == k0)      ? 0x3F80u : 0u;
        unsigned hi  = (l32 == k0 + 1)  ? 0x3F80u : 0u;
        Ilo.u[j] = lo | (hi << 16);
        unsigned lo2 = (l32 == 16 + k0)     ? 0x3F80u : 0u;
        unsigned hi2 = (l32 == 16 + k0 + 1) ? 0x3F80u : 0u;
        Ihi.u[j] = lo2 | (hi2 << 16);
    }

    size_t px1[2];
    #pragma unroll
    for (int t = 0; t < 2; ++t) {
        const int gwin = gw0 + 2 * t + (l32 >> 4);
        const int b = gwin / 2304;
        const int rem = gwin % 2304;
        const int Y = rem / 48, X = rem % 48;
        const int yy = Y * 4 + ((l32 >> 2) & 3);
        const int xx = X * 4 + (l32 & 3);
        px1[t] = ((size_t)b * HW + (size_t)yy * 192 + xx) * 128;
    }

    FragW qf[2], kf[2];
    #pragma unroll
    for (int t = 0; t < 2; ++t) {
        const char* rec = xh + px1[t];
        FragW xw[4];
        #pragma unroll
        for (int cc = 0; cc < 4; ++cc)
            xw[cc].s = *(const short8*)(rec + cc * 32 + 16 * h);

        f32x16 dqk = zf;
        #pragma unroll
        for (int cc = 0; cc < 4; ++cc)
            dqk = __builtin_amdgcn_mfma_f32_32x32x16_bf16(wqkf[cc].s, xw[cc].s, dqk, 0, 0, 0);

        {
            float q0[8];
            #pragma unroll
            for (int r = 0; r < 8; ++r) q0[r] = (dqk[r] + bqv[r]) * LOG2E;
            unsigned A0 = pk2(q0[0], q0[1]), B0 = pk2(q0[2], q0[3]);
            unsigned C0 = pk2(q0[4], q0[5]), D0 = pk2(q0[6], q0[7]);
            plswap(A0, C0); plswap(B0, D0);
            qf[t].u[0] = A0; qf[t].u[1] = B0; qf[t].u[2] = C0; qf[t].u[3] = D0;
        }
        {
            float k0[8];
            #pragma unroll
            for (int r = 0; r < 8; ++r) k0[r] = dqk[8 + r] + bkv[r];
            unsigned A0 = pk2(k0[0], k0[1]), B0 = pk2(k0[2], k0[3]);
            unsigned C0 = pk2(k0[4], k0[5]), D0 = pk2(k0[6], k0[7]);
            plswap(A0, C0); plswap(B0, D0);
            kf[t].u[0] = A0; kf[t].u[1] = B0; kf[t].u[2] = C0; kf[t].u[3] = D0;
        }

        #pragma unroll
        for (int ot = 0; ot < 2; ++ot) {
            f32x16 dv = zf;
            #pragma unroll
            for (int cc = 0; cc < 4; ++cc)
                dv = __builtin_amdgcn_mfma_f32_32x32x16_bf16(wvf[ot][cc].s, xw[cc].s, dv, 0, 0, 0);
            #pragma unroll
            for (int r = 0; r < 16; ++r) {
                const int ch = ot * 32 + (r & 3) + 8 * (r >> 2) + 4 * h;
                *(unsigned short*)(VsW + ((ch * 128 + 2 * (t * 32 + l32)) ^ ((ch & 7) << 4)))
                    = f2bf(dv[r] + bvv[ot][r]);
            }
        }
    }
    __syncthreads();

    const float g = gamma[0];
    const bool wa = (l32 < 16);

    #pragma unroll
    for (int t = 0; t < 2; ++t) {
        f32x16 sT = __builtin_amdgcn_mfma_f32_32x32x16_bf16(kf[t].s, qf[t].s, zf, 0, 0, 0);

        float e[8];
        #pragma unroll
        for (int j = 0; j < 8; ++j) e[j] = fexp2(wa ? sT[j] : sT[8 + j]);
        float ls = ((e[0] + e[1]) + (e[2] + e[3])) + ((e[4] + e[5]) + (e[6] + e[7]));
        ls += __shfl_xor(ls, 32);

        unsigned A0 = pk2(e[0], e[1]), B0 = pk2(e[2], e[3]);
        unsigned C0 = pk2(e[4], e[5]), D0 = pk2(e[6], e[7]);
        plswap(A0, C0); plswap(B0, D0);
        FragW pa, pb;
        pa.u[0] = wa ? A0 : 0u; pa.u[1] = wa ? B0 : 0u;
        pa.u[2] = wa ? C0 : 0u; pa.u[3] = wa ? D0 : 0u;
        pb.u[0] = wa ? 0u : A0; pb.u[1] = wa ? 0u : B0;
        pb.u[2] = wa ? 0u : C0; pb.u[3] = wa ? 0u : D0;

        f32x16 acc0 = zf, acc1 = zf;
        #pragma unroll
        for (int wsx = 0; wsx < 2; ++wsx) {
            const short8 pfrag = wsx ? pb.s : pa.s;
            const int mbase = t * 64 + wsx * 32 + 16 * h;
            const int ch0 = l32, ch1 = 32 + l32;
            const short8 v0 = *(const short8*)(VsW + ((ch0 * 128 + mbase) ^ ((ch0 & 7) << 4)));
            const short8 v1 = *(const short8*)(VsW + ((ch1 * 128 + mbase) ^ ((ch1 & 7) << 4)));
            acc0 = __builtin_amdgcn_mfma_f32_32x32x16_bf16(v0, pfrag, acc0, 0, 0, 0);
            acc1 = __builtin_amdgcn_mfma_f32_32x32x16_bf16(v1, pfrag, acc1, 0, 0, 0);
        }

        const float inv = 1.f / ls;

        // residual from own record via identity MFMA (exact D-layout)
        char* rec = xh + px1[t];
        FragW x0, x1, x2, x3;
        x0.s = *(const short8*)(rec + 0 * 32 + 16 * h);
        x1.s = *(const short8*)(rec + 1 * 32 + 16 * h);
        x2.s = *(const short8*)(rec + 2 * 32 + 16 * h);
        x3.s = *(const short8*)(rec + 3 * 32 + 16 * h);
        f32x16 r01 = __builtin_amdgcn_mfma_f32_32x32x16_bf16(Ihi.s, x1.s, zf, 0, 0, 0);
        r01 = __builtin_amdgcn_mfma_f32_32x32x16_bf16(Ilo.s, x0.s, r01, 0, 0, 0);
        f32x16 r23 = __builtin_amdgcn_mfma_f32_32x32x16_bf16(Ihi.s, x3.s, zf, 0, 0, 0);
        r23 = __builtin_amdgcn_mfma_f32_32x32x16_bf16(Ilo.s, x2.s, r23, 0, 0, 0);

        #pragma unroll
        for (int q = 0; q < 4; ++q) {
            const float a0 = fmaf(g, acc0[4*q+0] * inv, r01[4*q+0]);
            const float a1 = fmaf(g, acc0[4*q+1] * inv, r01[4*q+1]);
            const float a2 = fmaf(g, acc0[4*q+2] * inv, r01[4*q+2]);
            const float a3 = fmaf(g, acc0[4*q+3] * inv, r01[4*q+3]);
            uint2 wA; wA.x = pk2(a0, a1); wA.y = pk2(a2, a3);
            *(uint2*)(rec + 16 * q + 8 * h) = wA;
            const float b0 = fmaf(g, acc1[4*q+0] * inv, r23[4*q+0]);
            const float b1 = fmaf(g, acc1[4*q+1] * inv, r23[4*q+1]);
            const float b2 = fmaf(g, acc1[4*q+2] * inv, r23[4*q+2]);
            const float b3 = fmaf(g, acc1[4*q+3] * inv, r23[4*q+3]);
            uint2 wB; wB.x = pk2(b0, b1); wB.y = pk2(b2, b3);
            *(uint2*)(rec + 64 + 16 * q + 8 * h) = wB;
        }
    }
}

// ---------------- K3: 8x8 chess proj + attention + final fold, in-place ------
#define KT_OFF 0
#define VS_OFF 18432

__global__ __launch_bounds__(576) void attn2n_kernel(
    char* __restrict__ xh,
    const float* __restrict__ wq, const float* __restrict__ bq,
    const float* __restrict__ wk, const float* __restrict__ bk,
    const float* __restrict__ wv, const float* __restrict__ bv,
    const float* __restrict__ gamma)
{
    __shared__ char smem[92160];   // Kt 18432 + Vs 73728

    const int wid = blockIdx.x;
    const int b  = wid >> 6;
    const int a  = wid & 7;
    const int c0 = (wid >> 3) & 7;

    const int tid = threadIdx.x;
    const int wv_id = tid >> 6;
    const int l32 = tid & 31;
    const int h   = (tid >> 5) & 1;
    const int n0  = wv_id * 64;

    f32x16 zf;
    #pragma unroll
    for (int r = 0; r < 16; ++r) zf[r] = 0.f;

    FragW wqkf[4], wvf[2][4];
    {
        const float4* wrow4 = (const float4*)((l32 < 16) ? (wq + l32 * 64)
                                                         : (wk + (l32 - 16) * 64));
        #pragma unroll
        for (int cc = 0; cc < 4; ++cc) {
            const float4 a4 = wrow4[cc * 4 + 2 * h];
            const float4 b4 = wrow4[cc * 4 + 2 * h + 1];
            wqkf[cc].u[0] = pk2(a4.x, a4.y); wqkf[cc].u[1] = pk2(a4.z, a4.w);
            wqkf[cc].u[2] = pk2(b4.x, b4.y); wqkf[cc].u[3] = pk2(b4.z, b4.w);
        }
        #pragma unroll
        for (int ot = 0; ot < 2; ++ot) {
            const float4* wvr4 = (const float4*)(wv + (size_t)(ot * 32 + l32) * 64);
            #pragma unroll
            for (int cc = 0; cc < 4; ++cc) {
                const float4 a4 = wvr4[cc * 4 + 2 * h];
                const float4 b4 = wvr4[cc * 4 + 2 * h + 1];
                wvf[ot][cc].u[0] = pk2(a4.x, a4.y); wvf[ot][cc].u[1] = pk2(a4.z, a4.w);
                wvf[ot][cc].u[2] = pk2(b4.x, b4.y); wvf[ot][cc].u[3] = pk2(b4.z, b4.w);
            }
        }
    }
    float bias_qk[16], bvv[2][16];
    #pragma unroll
    for (int r = 0; r < 8; ++r) {
        const int c = (r & 3) + 8 * (r >> 2) + 4 * h;
        bias_qk[r] = bq[c];
        bias_qk[8 + r] = bk[c];
    }
    #pragma unroll
    for (int ot = 0; ot < 2; ++ot)
        #pragma unroll
        for (int r = 0; r < 16; ++r)
            bvv[ot][r] = bv[ot * 32 + (r & 3) + 8 * (r >> 2) + 4 * h];

    // identity A-frags (residual lift)
    FragW Ilo, Ihi;
    #pragma unroll
    for (int j = 0; j < 4; ++j) {
        const int k0 = 8 * h + 2 * j;
        unsigned lo  = (l32 == k0)      ? 0x3F80u : 0u;
        unsigned hi  = (l32 == k0 + 1)  ? 0x3F80u : 0u;
        Ilo.u[j] = lo | (hi << 16);
        unsigned lo2 = (l32 == 16 + k0)     ? 0x3F80u : 0u;
        unsigned hi2 = (l32 == 16 + k0 + 1) ? 0x3F80u : 0u;
        Ihi.u[j] = lo2 | (hi2 << 16);
    }
    // all-ones A-frag (softmax denominator via MFMA column-sum)
    FragW ones;
    ones.u[0] = ones.u[1] = ones.u[2] = ones.u[3] = 0x3F803F80u;

    size_t prec[2];
    FragW qfr[2];
    #pragma unroll
    for (int t = 0; t < 2; ++t) {
        const int m = n0 + t * 32 + l32;
        const int i = m / 24, j = m - i * 24;
        prec[t] = ((size_t)b * HW + (size_t)(a + 8 * i) * 192 + (c0 + 8 * j)) * 128;
        const char* rec = xh + prec[t];

        FragW xw[4];
        #pragma unroll
        for (int cc = 0; cc < 4; ++cc)
            xw[cc].s = *(const short8*)(rec + cc * 32 + 16 * h);

        f32x16 dqk = zf;
        #pragma unroll
        for (int cc = 0; cc < 4; ++cc)
            dqk = __builtin_amdgcn_mfma_f32_32x32x16_bf16(wqkf[cc].s, xw[cc].s, dqk, 0, 0, 0);

        {   // Q B-frag, pre-scaled by log2(e) so the loop uses exp2 directly
            float q0[8];
            #pragma unroll
            for (int r = 0; r < 8; ++r) q0[r] = (dqk[r] + bias_qk[r]) * LOG2E;
            unsigned A0 = pk2(q0[0], q0[1]), B0 = pk2(q0[2], q0[3]);
            unsigned C0 = pk2(q0[4], q0[5]), D0 = pk2(q0[6], q0[7]);
            plswap(A0, C0); plswap(B0, D0);
            qfr[t].u[0] = A0; qfr[t].u[1] = B0; qfr[t].u[2] = C0; qfr[t].u[3] = D0;
        }
        #pragma unroll
        for (int r = 8; r < 16; ++r) {
            const int c = (r & 3) + 8 * ((r >> 2) & 1) + 4 * h;
            *(unsigned short*)(smem + KT_OFF + ((m * 32 + 2 * c) ^ (((m >> 2) & 3) << 4)))
                = f2bf(dqk[r] + bias_qk[r]);
        }
        #pragma unroll
        for (int ot = 0; ot < 2; ++ot) {
            f32x16 dv = zf;
            #pragma unroll
            for (int cc = 0; cc < 4; ++cc)
                dv = __builtin_amdgcn_mfma_f32_32x32x16_bf16(wvf[ot][cc].s, xw[cc].s, dv, 0, 0, 0);
            #pragma unroll
            for (int r = 0; r < 16; ++r) {
                const int ch = ot * 32 + (r & 3) + 8 * (r >> 2) + 4 * h;
                *(unsigned short*)(smem + VS_OFF + ((ch * 1152 + 2 * m) ^ ((ch & 7) << 4)))
                    = f2bf(dv[r] + bvv[ot][r]);
            }
        }
    }
    __syncthreads();

    const short8 qf0 = qfr[0].s, qf1 = qfr[1].s;
    f32x16 accA = zf, accB = zf, accC = zf, accD = zf;
    f32x16 accS0 = zf, accS1 = zf;   // softmax denominators via ones-MFMA
    const int chA = l32, chB = 32 + l32;
    const int swzA = (chA & 7) << 4, swzB = (chB & 7) << 4;

    // K-fragment register prefetch (tile 0)
    short8 kfc = *(const short8*)(smem + KT_OFF + ((l32 * 32 + 16 * h) ^ (((l32 >> 2) & 3) << 4)));

    #pragma unroll 1
    for (int mt = 0; mt < 18; ++mt) {
        const int m0 = mt * 32;

        // prefetch next K-fragment before the compute chain
        short8 kfn = kfc;
        if (mt < 17) {
            const int mr = m0 + 32 + l32;
            kfn = *(const short8*)(smem + KT_OFF + ((mr * 32 + 16 * h) ^ (((mr >> 2) & 3) << 4)));
        }

        f32x16 s0 = __builtin_amdgcn_mfma_f32_32x32x16_bf16(kfc, qf0, zf, 0, 0, 0);
        f32x16 s1 = __builtin_amdgcn_mfma_f32_32x32x16_bf16(kfc, qf1, zf, 0, 0, 0);

        const short8 vA0 = *(const short8*)(smem + VS_OFF + ((chA * 1152 + 2 * (m0 + 8 * h)) ^ swzA));
        const short8 vA1 = *(const short8*)(smem + VS_OFF + ((chA * 1152 + 2 * (m0 + 16 + 8 * h)) ^ swzA));
        const short8 vB0 = *(const short8*)(smem + VS_OFF + ((chB * 1152 + 2 * (m0 + 8 * h)) ^ swzB));
        const short8 vB1 = *(const short8*)(smem + VS_OFF + ((chB * 1152 + 2 * (m0 + 16 + 8 * h)) ^ swzB));

        #pragma unroll
        for (int r = 0; r < 16; ++r) s0[r] = fexp2(s0[r]);
        #pragma unroll
        for (int r = 0; r < 16; ++r) s1[r] = fexp2(s1[r]);

        FragW pf00, pf01, pf10, pf11;
        {
            unsigned A0 = pk2(s0[0], s0[1]), B0 = pk2(s0[2], s0[3]);
            unsigned C0 = pk2(s0[4], s0[5]), D0 = pk2(s0[6], s0[7]);
            plswap(A0, C0); plswap(B0, D0);
            pf00.u[0] = A0; pf00.u[1] = B0; pf00.u[2] = C0; pf00.u[3] = D0;
            unsigned E0 = pk2(s0[8], s0[9]),  F0 = pk2(s0[10], s0[11]);
            unsigned G0 = pk2(s0[12], s0[13]), H0 = pk2(s0[14], s0[15]);
            plswap(E0, G0); plswap(F0, H0);
            pf01.u[0] = E0; pf01.u[1] = F0; pf01.u[2] = G0; pf01.u[3] = H0;
            unsigned A1 = pk2(s1[0], s1[1]), B1 = pk2(s1[2], s1[3]);
            unsigned C1 = pk2(s1[4], s1[5]), D1 = pk2(s1[6], s1[7]);
            plswap(A1, C1); plswap(B1, D1);
            pf10.u[0] = A1; pf10.u[1] = B1; pf10.u[2] = C1; pf10.u[3] = D1;
            unsigned E1 = pk2(s1[8], s1[9]),  F1 = pk2(s1[10], s1[11]);
            unsigned G1 = pk2(s1[12], s1[13]), H1 = pk2(s1[14], s1[15]);
            plswap(E1, G1); plswap(F1, H1);
            pf11.u[0] = E1; pf11.u[1] = F1; pf11.u[2] = G1; pf11.u[3] = H1;
        }

        accA = __builtin_amdgcn_mfma_f32_32x32x16_bf16(vA0, pf00.s, accA, 0, 0, 0);
        accA = __builtin_amdgcn_mfma_f32_32x32x16_bf16(vA1, pf01.s, accA, 0, 0, 0);
        accB = __builtin_amdgcn_mfma_f32_32x32x16_bf16(vB0, pf00.s, accB, 0, 0, 0);
        accB = __builtin_amdgcn_mfma_f32_32x32x16_bf16(vB1, pf01.s, accB, 0, 0, 0);
        accC = __builtin_amdgcn_mfma_f32_32x32x16_bf16(vA0, pf10.s, accC, 0, 0, 0);
        accC = __builtin_amdgcn_mfma_f32_32x32x16_bf16(vA1, pf11.s, accC, 0, 0, 0);
        accD = __builtin_amdgcn_mfma_f32_32x32x16_bf16(vB0, pf10.s, accD, 0, 0, 0);
        accD = __builtin_amdgcn_mfma_f32_32x32x16_bf16(vB1, pf11.s, accD, 0, 0, 0);

        // denominator: column sums of bf16(P) via all-ones A-frag
        accS0 = __builtin_amdgcn_mfma_f32_32x32x16_bf16(ones.s, pf00.s, accS0, 0, 0, 0);
        accS0 = __builtin_amdgcn_mfma_f32_32x32x16_bf16(ones.s, pf01.s, accS0, 0, 0, 0);
        accS1 = __builtin_amdgcn_mfma_f32_32x32x16_bf16(ones.s, pf10.s, accS1, 0, 0, 0);
        accS1 = __builtin_amdgcn_mfma_f32_32x32x16_bf16(ones.s, pf11.s, accS1, 0, 0, 0);

        kfc = kfn;
    }

    const float g2 = gamma[0];
    const float inv0 = 1.f / accS0[0], inv1 = 1.f / accS1[0];

    // final = g2 * att + out1 (residual via identity MFMA), in-place per tile
    #pragma unroll
    for (int t = 0; t < 2; ++t) {
        char* rec = xh + prec[t];
        FragW x0, x1, x2, x3;
        x0.s = *(const short8*)(rec + 0 * 32 + 16 * h);
        x1.s = *(const short8*)(rec + 1 * 32 + 16 * h);
        x2.s = *(const short8*)(rec + 2 * 32 + 16 * h);
        x3.s = *(const short8*)(rec + 3 * 32 + 16 * h);
        f32x16 r01 = __builtin_amdgcn_mfma_f32_32x32x16_bf16(Ihi.s, x1.s, zf, 0, 0, 0);
        r01 = __builtin_amdgcn_mfma_f32_32x32x16_bf16(Ilo.s, x0.s, r01, 0, 0, 0);
        f32x16 r23 = __builtin_amdgcn_mfma_f32_32x32x16_bf16(Ihi.s, x3.s, zf, 0, 0, 0);
        r23 = __builtin_amdgcn_mfma_f32_32x32x16_bf16(Ilo.s, x2.s, r23, 0, 0, 0);

        const f32x16 aclo = t ? accC : accA;
        const f32x16 achi = t ? accD : accB;
        const float inv = t ? inv1 : inv0;

        #pragma unroll
        for (int q = 0; q < 4; ++q) {
            const float a0 = fmaf(g2, aclo[4*q+0] * inv, r01[4*q+0]);
            const float a1 = fmaf(g2, aclo[4*q+1] * inv, r01[4*q+1]);
            const float a2 = fmaf(g2, aclo[4*q+2] * inv, r01[4*q+2]);
            const float a3 = fmaf(g2, aclo[4*q+3] * inv, r01[4*q+3]);
            uint2 wA; wA.x = pk2(a0, a1); wA.y = pk2(a2, a3);
            *(uint2*)(rec + 16 * q + 8 * h) = wA;
            const float b0 = fmaf(g2, achi[4*q+0] * inv, r23[4*q+0]);
            const float b1 = fmaf(g2, achi[4*q+1] * inv, r23[4*q+1]);
            const float b2 = fmaf(g2, achi[4*q+2] * inv, r23[4*q+2]);
            const float b3 = fmaf(g2, achi[4*q+3] * inv, r23[4*q+3]);
            uint2 wB; wB.x = pk2(b0, b1); wB.y = pk2(b2, b3);
            *(uint2*)(rec + 64 + 16 * q + 8 * h) = wB;
        }
    }
}

// ---------------- K4: NHWC bf16 records -> out NCHW f32 (write-only) ---------
__global__ __launch_bounds__(256) void to_nchw_kernel(
    float* __restrict__ out, const char* __restrict__ xh)
{
    __shared__ char smem[24576];

    const int bid = blockIdx.x;
    const int b = bid / 192, y = bid % 192;
    const int tid = threadIdx.x;

    const char* src = xh + ((size_t)b * HW + (size_t)y * 192) * 128;
    #pragma unroll
    for (int k = 0; k < 6; ++k) {
        const int off = k * 4096 + tid * 16;
        const int xq = off >> 7;
        const int gq = (off >> 4) & 7;
        const short8 v = *(const short8*)(src + off);
        *(short8*)(smem + (xq << 7) + (((gq ^ (xq & 7)) << 4))) = v;
    }
    __syncthreads();

    const int w = tid >> 6, lane = tid & 63;
    const size_t rowbase = (size_t)b * 64 * HW + (size_t)y * 192;

    #pragma unroll
    for (int it = 0; it < 24; ++it) {
        const int tt = it * 4 + w;
        const int chp = tt & 31;
        const int xb = tt >> 5;
        const int xx = xb * 64 + lane;
        const int byte_in_rec = chp * 4;
        const int gq = byte_in_rec >> 4;
        const unsigned v = *(const unsigned*)(smem + (xx << 7)
                            + ((gq ^ (xx & 7)) << 4) + (byte_in_rec & 15));
        const size_t o0 = rowbase + (size_t)(2 * chp) * HW + xx;
        out[o0]      = BLO(v);
        out[o0 + HW] = BHI(v);
    }
}

extern "C" void kernel_launch(void* const* d_in, const int* in_sizes, int n_in,
                              void* d_out, int out_size, void* d_ws, size_t ws_size,
                              hipStream_t stream)
{
    const float* x   = (const float*)d_in[0];
    const float* wq1 = (const float*)d_in[1];
    const float* bq1 = (const float*)d_in[2];
    const float* wk1 = (const float*)d_in[3];
    const float* bk1 = (const float*)d_in[4];
    const float* wv1 = (const float*)d_in[5];
    const float* bv1 = (const float*)d_in[6];
    const float* wq2 = (const float*)d_in[7];
    const float* bq2 = (const float*)d_in[8];
    const float* wk2 = (const float*)d_in[9];
    const float* bk2 = (const float*)d_in[10];
    const float* wv2 = (const float*)d_in[11];
    const float* bv2 = (const float*)d_in[12];
    const float* g1  = (const float*)d_in[13];
    const float* g2  = (const float*)d_in[14];
    float* out = (float*)d_out;
    char* xh = (char*)d_ws;

    to_nhwc_kernel<<<dim3(1536), dim3(256), 0, stream>>>(x, xh);

    attn1n_kernel<<<dim3(1152), dim3(256), 0, stream>>>(
        xh, wq1, bq1, wk1, bk1, wv1, bv1, g1);

    attn2n_kernel<<<dim3(512), dim3(576), 0, stream>>>(
        xh, wq2, bq2, wk2, bk2, wv2, bv2, g2);

    to_nchw_kernel<<<dim3(1536), dim3(256), 0, stream>>>(out, xh);
}